// Round 6
// baseline (206.830 us; speedup 1.0000x reference)
//
#include <hip/hip_runtime.h>
#include <stdint.h>

#define TT 512
#define DD 1024
#define NN 65536
#define HH 150
#define LL 17

typedef __bf16 bf16_t;
typedef short shortx8 __attribute__((ext_vector_type(8)));
typedef short shortx4 __attribute__((ext_vector_type(4)));
typedef float f32x4 __attribute__((ext_vector_type(4)));

static __device__ __forceinline__ short f2bf(float f) {
  return (short)__builtin_bit_cast(unsigned short, (bf16_t)f);
}

// ---------------------------------------------------------------------------
// Prep (UNCHANGED from round 5): (optional) xs fp32->bf16, W1 repack ->
// Bp[64 kb][10 cb][64 lane][8 j] (= W1[kb*32+(l>>4)*8+j][cb*16+(l&15)],
// zero-pad cols>=150), W2 -> W2p[5 ks][2 cb2][64 lane][8 j].
// ---------------------------------------------------------------------------
__global__ __launch_bounds__(256) void prep_all(
    const float* __restrict__ xs, const float* __restrict__ W1,
    const float* __restrict__ W2, short* __restrict__ xs16,
    short* __restrict__ Bp, short* __restrict__ W2p, int do_cvt)
{
  int b = blockIdx.x;
  if (do_cvt && b < 2048) {
    int t = b * 256 + threadIdx.x;
#pragma unroll
    for (int i = 0; i < 8; ++i) {
      int id = t + i * 524288;
      f32x4 v = reinterpret_cast<const f32x4*>(xs)[id];
      shortx4 o;
      o[0] = f2bf(v[0]); o[1] = f2bf(v[1]); o[2] = f2bf(v[2]); o[3] = f2bf(v[3]);
      reinterpret_cast<shortx4*>(xs16)[id] = o;
    }
    return;
  }
  int rb = do_cvt ? b - 2048 : b;
  int task = rb * 256 + threadIdx.x;
  const int NW1 = 64 * 10 * 64;
  if (task < NW1) {
    int kb  = task / 640;
    int rem = task - kb * 640;
    int cb = rem >> 6, l = rem & 63;
    int col  = cb * 16 + (l & 15);
    int krow = kb * 32 + (l >> 4) * 8;
    shortx8 v;
#pragma unroll
    for (int j = 0; j < 8; ++j) {
      float f = (col < HH) ? W1[(krow + j) * HH + col] : 0.f;
      v[j] = f2bf(f);
    }
    *reinterpret_cast<shortx8*>(Bp + task * 8) = v;
  } else if (task < NW1 + 640) {
    int t2 = task - NW1;
    int kb  = t2 >> 7;
    int rem = t2 & 127;
    int cb = rem >> 6, l = rem & 63;
    int col  = cb * 16 + (l & 15);
    int krow = kb * 32 + (l >> 4) * 8;
    shortx8 v;
#pragma unroll
    for (int j = 0; j < 8; ++j) {
      int r = krow + j;
      float f = (r < HH && col < LL) ? W2[r * LL + col] : 0.f;
      v[j] = f2bf(f);
    }
    *reinterpret_cast<shortx8*>(W2p + t2 * 8) = v;
  }
}

// ---------------------------------------------------------------------------
// Main v3: barrier-light, LDS-free GEMM1. 512 blocks x 256 threads; wave
// (wr=wv>>1, wc=wv&1) owns 64 rows x 80 hcols. W1 fragments read DIRECTLY
// from global (Bp streams through L1/L2, all waves in phase); feats gathered
// global->reg. Swapped-operand MFMA: acc = mfma(W1frag, featfrag) computes
// h^T tiles so lane layout (span=l15, hcol=kg*4+i) IS the GEMM2 A-fragment.
// Epilogue: relu+b1 in-reg -> h LDS tile [128][168 shorts] (b64 writes,
// b128 reads, ~2-way conflicts = free) -> one __syncthreads -> GEMM2
// (wc0: labels 0-15, wc1: label 16) -> out + b2.
// ---------------------------------------------------------------------------
template<int XS16>
__global__ __launch_bounds__(256, 2) void span_mlp3(
    const void* __restrict__ xsv, const int* __restrict__ spans,
    const int* __restrict__ bids, const short* __restrict__ Bp,
    const float* __restrict__ b1, const short* __restrict__ W2p,
    const float* __restrict__ b2, float* __restrict__ out)
{
  __shared__ __align__(16) char lds[43008];   // h tile: 128 rows x 168 shorts

  const int tid  = threadIdx.x;
  const int wv   = tid >> 6;
  const int wr   = wv >> 1;                   // row-group 0/1 (64 rows each)
  const int wc   = wv & 1;                    // hcol-half 0/1 (80 cols each)
  const int lane = tid & 63;
  const int l15  = lane & 15;
  const int kg   = lane >> 4;
  const int blk  = blockIdx.x;

  // gathered feature row base byte-pointers [rf][begin/end]
  const char* abase[4][2];
  const int elt = XS16 ? 2 : 4;
#pragma unroll
  for (int rf = 0; rf < 4; ++rf) {
    int r  = blk * 128 + wr * 64 + rf * 16 + l15;
    int bb = bids[r];
    int s0 = spans[2 * r + 0];
    int s1 = spans[2 * r + 1];
    abase[rf][0] = (const char*)xsv + (size_t)(bb * TT + s0) * DD * elt;
    abase[rf][1] = (const char*)xsv + (size_t)(bb * TT + s1) * DD * elt;
  }

  // this wave's W1-fragment stream base (cb-half selected by wc)
  const char* bp = (const char*)Bp + (wc * 5) * 1024 + lane * 16;

  f32x4 acc[4][5];
  {
    f32x4 z = {0.f, 0.f, 0.f, 0.f};
#pragma unroll
    for (int rf = 0; rf < 4; ++rf)
#pragma unroll
      for (int cb = 0; cb < 5; ++cb) acc[rf][cb] = z;
  }

  shortx8 w1A[5], w1B[5], ftA[4], ftB[4];

#define LOADW1(buf, g) do { _Pragma("unroll") \
    for (int cb = 0; cb < 5; ++cb) \
      buf[cb] = *reinterpret_cast<const shortx8*>(bp + ((g) * 10 + cb) * 1024); \
  } while (0)

#define LOADFT(buf, g) do { \
    const int side_ = ((g) >= 32) ? 1 : 0; \
    const int ko_ = ((g) & 31) * (XS16 ? 64 : 128) + kg * (XS16 ? 16 : 32); \
    _Pragma("unroll") \
    for (int rf = 0; rf < 4; ++rf) { \
      if constexpr (XS16) { \
        buf[rf] = *reinterpret_cast<const shortx8*>(abase[rf][side_] + ko_); \
      } else { \
        f32x4 x_ = *reinterpret_cast<const f32x4*>(abase[rf][side_] + ko_); \
        f32x4 y_ = *reinterpret_cast<const f32x4*>(abase[rf][side_] + ko_ + 16); \
        shortx8 t_; \
        t_[0]=f2bf(x_[0]); t_[1]=f2bf(x_[1]); t_[2]=f2bf(x_[2]); t_[3]=f2bf(x_[3]); \
        t_[4]=f2bf(y_[0]); t_[5]=f2bf(y_[1]); t_[6]=f2bf(y_[2]); t_[7]=f2bf(y_[3]); \
        buf[rf] = t_; \
      } \
    } \
  } while (0)

#define MFMA_STEP(w1, ft) do { _Pragma("unroll") \
    for (int rf = 0; rf < 4; ++rf) \
      _Pragma("unroll") \
      for (int cb = 0; cb < 5; ++cb) \
        acc[rf][cb] = __builtin_amdgcn_mfma_f32_16x16x32_bf16( \
            w1[cb], ft[rf], acc[rf][cb], 0, 0, 0); \
  } while (0)

  // software pipeline over 64 K-substeps (K=32 each), depth-1 prefetch
  LOADW1(w1A, 0);
  LOADFT(ftA, 0);
  for (int gp = 0; gp < 32; ++gp) {
    int g = 2 * gp;
    LOADW1(w1B, g + 1);
    LOADFT(ftB, g + 1);
    MFMA_STEP(w1A, ftA);
    if (gp < 31) {
      LOADW1(w1A, g + 2);
      LOADFT(ftA, g + 2);
    }
    MFMA_STEP(w1B, ftB);
    // phase-align waves every 8 substeps so same-CU waves share the W1
    // stream through L1 (bare barrier: no waitcnt drain, loads stay in
    // flight; compiler-inserted waitcnts handle the register data deps)
    if ((gp & 3) == 3) __builtin_amdgcn_s_barrier();
  }
#undef LOADW1
#undef LOADFT
#undef MFMA_STEP

  // ---- epilogue: bias+relu in-reg -> h LDS tile (row=span, col=hcol)
  short* hS = (short*)lds;
#pragma unroll
  for (int cb = 0; cb < 5; ++cb) {
    f32x4 bv = *reinterpret_cast<const f32x4*>(b1 + wc * 80 + cb * 16 + kg * 4);
#pragma unroll
    for (int rf = 0; rf < 4; ++rf) {
      f32x4 v = acc[rf][cb] + bv;
      shortx4 hv;
      hv[0] = f2bf(fmaxf(v[0], 0.f));
      hv[1] = f2bf(fmaxf(v[1], 0.f));
      hv[2] = f2bf(fmaxf(v[2], 0.f));
      hv[3] = f2bf(fmaxf(v[3], 0.f));
      int row = wr * 64 + rf * 16 + l15;                 // span-local
      int col = wc * 80 + cb * 16 + kg * 4;              // hcol
      *reinterpret_cast<shortx4*>((char*)hS + row * 336 + col * 2) = hv;
    }
  }
  __syncthreads();

  // ---- GEMM2: wave handles label block cb2 = wc (0: labels 0-15, 1: 16)
  f32x4 acc2[4];
  {
    f32x4 z = {0.f, 0.f, 0.f, 0.f};
#pragma unroll
    for (int rf = 0; rf < 4; ++rf) acc2[rf] = z;
  }
#pragma unroll
  for (int ks = 0; ks < 5; ++ks) {
    shortx8 wf = *reinterpret_cast<const shortx8*>(
        W2p + ((ks * 2 + wc) * 64 + lane) * 8);
#pragma unroll
    for (int rf = 0; rf < 4; ++rf) {
      shortx8 af = *reinterpret_cast<const shortx8*>(
          (const char*)hS + (wr * 64 + rf * 16 + l15) * 336 + ks * 64 + kg * 16);
      acc2[rf] = __builtin_amdgcn_mfma_f32_16x16x32_bf16(af, wf, acc2[rf], 0, 0, 0);
    }
  }

  int col = wc * 16 + l15;
  if (col < LL) {
    float bb = b2[col];
#pragma unroll
    for (int rf = 0; rf < 4; ++rf)
#pragma unroll
      for (int i = 0; i < 4; ++i) {
        int row = blk * 128 + wr * 64 + rf * 16 + kg * 4 + i;
        out[(size_t)row * LL + col] = acc2[rf][i] + bb;
      }
  }
}

extern "C" void kernel_launch(void* const* d_in, const int* in_sizes, int n_in,
                              void* d_out, int out_size, void* d_ws, size_t ws_size,
                              hipStream_t stream) {
  const float* xs    = (const float*)d_in[0];
  const int*   spans = (const int*)d_in[1];
  const int*   bids  = (const int*)d_in[2];
  const float* W1    = (const float*)d_in[3];
  const float* b1    = (const float*)d_in[4];
  const float* W2    = (const float*)d_in[5];
  const float* b2    = (const float*)d_in[6];
  float* out = (float*)d_out;

  const size_t XS16B = 33554432;            // 16,777,216 bf16
  const size_t WREQ  = XS16B + 655360 + 10240;

  if (ws_size >= WREQ) {
    short* xs16 = (short*)d_ws;
    short* Bp   = (short*)((char*)d_ws + XS16B);
    short* W2p  = Bp + 327680;
    prep_all<<<2211, 256, 0, stream>>>(xs, W1, W2, xs16, Bp, W2p, 1);
    span_mlp3<1><<<512, 256, 0, stream>>>(xs16, spans, bids, Bp, b1, W2p, b2, out);
  } else {
    short* Bp  = (short*)d_ws;
    short* W2p = Bp + 327680;
    prep_all<<<163, 256, 0, stream>>>(xs, W1, W2, nullptr, Bp, W2p, 0);
    span_mlp3<0><<<512, 256, 0, stream>>>(xs, spans, bids, Bp, b1, W2p, b2, out);
  }
}

// Round 7
// 148.734 us; speedup vs baseline: 1.3906x; 1.3906x over previous
//
#include <hip/hip_runtime.h>
#include <stdint.h>

#define TT 512
#define DD 1024
#define NN 65536
#define HH 150
#define LL 17

typedef __bf16 bf16_t;
typedef short shortx8 __attribute__((ext_vector_type(8)));
typedef short shortx4 __attribute__((ext_vector_type(4)));
typedef float f32x4 __attribute__((ext_vector_type(4)));

typedef __attribute__((address_space(1))) const void gconst_void;
typedef __attribute__((address_space(3))) void lds_void;

static __device__ __forceinline__ short f2bf(float f) {
  return (short)__builtin_bit_cast(unsigned short, (bf16_t)f);
}
static __device__ __forceinline__ float bf2f(short s) {
  unsigned u = ((unsigned)(unsigned short)s) << 16;
  return __builtin_bit_cast(float, u);
}

// ---------------------------------------------------------------------------
// Prep: W1 [2048][150] -> Bpp[32 kb][20 cb][64 lane][8 j] where fragment value
//   = W1[1024*half + kb*32 + (l>>4)*8 + j][hc],  cc = cb*16+(l&15),
//     half = cc>=160, hc = cc-160*half, zero if hc>=150.
// (cols 0..159 = W1a = begin-half rows 0..1023; cols 160..319 = W1b = rows
//  1024..2047). W2 -> W2p[5 ks][2 cb2][64 lane][8 j], zero-padded.
// ---------------------------------------------------------------------------
__global__ __launch_bounds__(256) void prep_w(
    const float* __restrict__ W1, const float* __restrict__ W2,
    short* __restrict__ Bpp, short* __restrict__ W2p)
{
  int task = blockIdx.x * 256 + threadIdx.x;
  const int NW1 = 32 * 20 * 64;               // 40960 fragments of 16B
  if (task < NW1) {
    int kb  = task / 1280;
    int rem = task - kb * 1280;
    int cb = rem >> 6, l = rem & 63;
    int cc   = cb * 16 + (l & 15);            // 0..319
    int half = (cc >= 160) ? 1 : 0;
    int hc   = cc - 160 * half;               // 0..159
    int krow = half * 1024 + kb * 32 + (l >> 4) * 8;
    shortx8 v;
#pragma unroll
    for (int j = 0; j < 8; ++j) {
      float f = (hc < HH) ? W1[(krow + j) * HH + hc] : 0.f;
      v[j] = f2bf(f);
    }
    *reinterpret_cast<shortx8*>(Bpp + task * 8) = v;
  } else if (task < NW1 + 640) {
    int t2 = task - NW1;
    int kb  = t2 >> 7;
    int rem = t2 & 127;
    int cb = rem >> 6, l = rem & 63;
    int col  = cb * 16 + (l & 15);
    int krow = kb * 32 + (l >> 4) * 8;
    shortx8 v;
#pragma unroll
    for (int j = 0; j < 8; ++j) {
      int r = krow + j;
      float f = (r < HH && col < LL) ? W2[r * LL + col] : 0.f;
      v[j] = f2bf(f);
    }
    *reinterpret_cast<shortx8*>(W2p + t2 * 8) = v;
  }
}

// ---------------------------------------------------------------------------
// K1: dense GEMM  H[16384][320] = xs_flat[16384][1024] @ [W1a|W1b], bf16 out,
// b1 pre-added to the Ha half (cols<150). 256 blocks x 512 threads; block =
// 64 rows x 320 cols; wave (wr=wv>>2, wc=wv&3) = 32 rows x 80 cols.
// B (W1) staged global_load_lds -> LDS dbuf (2 x 40KB), counted vmcnt(8) +
// raw barrier. A (xs) read fp32 coalesced global->reg, cvt in-reg, 1-chunk
// prefetch. MFMA operands SWAPPED (w1 first): lane then holds
// H[row = rfi*16+l15][cols cbl*16+kg*4 .. +3] -> direct shortx4 global store.
// ---------------------------------------------------------------------------
__global__ __launch_bounds__(512, 2) void k1_gemm(
    const float* __restrict__ xs, const short* __restrict__ Bpp,
    const float* __restrict__ b1, short* __restrict__ H)
{
  __shared__ __align__(16) char lds[81920];   // 2 x 40KB dbuf

  const int tid  = threadIdx.x;
  const int wv   = tid >> 6;
  const int wr   = wv >> 2;                   // 0/1: 32-row half
  const int wc   = wv & 3;                    // 0..3: 80-col quarter
  const int lane = tid & 63;
  const int l15  = lane & 15;
  const int kg   = lane >> 4;
  const int blk  = blockIdx.x;

  const char* ab[2];
#pragma unroll
  for (int rfi = 0; rfi < 2; ++rfi) {
    int row = blk * 64 + wr * 32 + rfi * 16 + l15;
    ab[rfi] = (const char*)xs + (size_t)row * 4096;
  }

  f32x4 acc[2][5];
  {
    f32x4 z = {0.f, 0.f, 0.f, 0.f};
#pragma unroll
    for (int rfi = 0; rfi < 2; ++rfi)
#pragma unroll
      for (int cbl = 0; cbl < 5; ++cbl) acc[rfi][cbl] = z;
  }

  shortx8 xbA[2][2], xbB[2][2];

  // stage chunk c (K-range c*64..+64, 40KB = 40 frags of 1KB) into buf p
#define STAGE(c, p) do { _Pragma("unroll") \
    for (int i = 0; i < 5; ++i) { \
      int f_ = wv * 5 + i;                     /* 0..39 */ \
      int s_ = f_ / 20, cbb_ = f_ % 20; \
      const char* g_ = (const char*)Bpp + \
          (size_t)(((2 * (c) + s_) * 20 + cbb_) * 64 + lane) * 16; \
      char* l_ = lds + (p) * 40960 + f_ * 1024; \
      __builtin_amdgcn_global_load_lds((gconst_void*)g_, (lds_void*)l_, 16, 0, 0); \
    } \
  } while (0)

#define LOADX(c, xb) do { _Pragma("unroll") \
    for (int rfi = 0; rfi < 2; ++rfi) \
      _Pragma("unroll") \
      for (int s = 0; s < 2; ++s) { \
        int off_ = (2 * (c) + s) * 128 + kg * 32; \
        f32x4 x_ = *reinterpret_cast<const f32x4*>(ab[rfi] + off_); \
        f32x4 y_ = *reinterpret_cast<const f32x4*>(ab[rfi] + off_ + 16); \
        shortx8 t_; \
        t_[0]=f2bf(x_[0]); t_[1]=f2bf(x_[1]); t_[2]=f2bf(x_[2]); t_[3]=f2bf(x_[3]); \
        t_[4]=f2bf(y_[0]); t_[5]=f2bf(y_[1]); t_[6]=f2bf(y_[2]); t_[7]=f2bf(y_[3]); \
        xb[rfi][s] = t_; \
      } \
  } while (0)

#define COMP(p, xb) do { _Pragma("unroll") \
    for (int s = 0; s < 2; ++s) { \
      shortx8 w1f[5]; \
      _Pragma("unroll") \
      for (int cbl = 0; cbl < 5; ++cbl) \
        w1f[cbl] = *reinterpret_cast<const shortx8*>( \
            lds + (p) * 40960 + (s * 20 + wc * 5 + cbl) * 1024 + lane * 16); \
      _Pragma("unroll") \
      for (int rfi = 0; rfi < 2; ++rfi) \
        _Pragma("unroll") \
        for (int cbl = 0; cbl < 5; ++cbl) \
          acc[rfi][cbl] = __builtin_amdgcn_mfma_f32_16x16x32_bf16( \
              w1f[cbl], xb[rfi][s], acc[rfi][cbl], 0, 0, 0); \
    } \
  } while (0)

  // counted-vmcnt barrier: drains the 5 stage loads (oldest); the 8 A-loads
  // for the next chunk stay in flight across the barrier.
#define WAITBAR() do { \
    asm volatile("s_waitcnt vmcnt(8)" ::: "memory"); \
    __builtin_amdgcn_s_barrier(); \
    __builtin_amdgcn_sched_barrier(0); \
  } while (0)

  STAGE(0, 0);
  LOADX(0, xbA);
  WAITBAR();

  for (int cp = 0; cp < 8; ++cp) {
    int c0 = 2 * cp;
    STAGE(c0 + 1, 1);
    LOADX(c0 + 1, xbB);
    COMP(0, xbA);
    WAITBAR();
    if (cp < 7) {
      STAGE(c0 + 2, 0);
      LOADX(c0 + 2, xbA);
    }
    COMP(1, xbB);
    if (cp < 7) WAITBAR();
  }
#undef STAGE
#undef LOADX
#undef COMP
#undef WAITBAR

  // epilogue: +b1 on Ha half (guarded: cols 150..159 and >=160 get 0),
  // cvt bf16, direct store (lane holds 4 consecutive H-cols for one row)
#pragma unroll
  for (int cbl = 0; cbl < 5; ++cbl) {
    int c0 = wc * 80 + cbl * 16 + kg * 4;     // H col of component 0
    f32x4 badd;
#pragma unroll
    for (int i = 0; i < 4; ++i)
      badd[i] = (c0 + i < HH) ? b1[c0 + i] : 0.f;
#pragma unroll
    for (int rfi = 0; rfi < 2; ++rfi) {
      f32x4 v = acc[rfi][cbl] + badd;
      shortx4 hv;
      hv[0] = f2bf(v[0]); hv[1] = f2bf(v[1]); hv[2] = f2bf(v[2]); hv[3] = f2bf(v[3]);
      int hrow = blk * 64 + wr * 32 + rfi * 16 + l15;
      *reinterpret_cast<shortx4*>(H + (size_t)hrow * 320 + c0) = hv;
    }
  }
}

// ---------------------------------------------------------------------------
// K2: per span: h = relu(Ha[rb] + Hb[re])  (b1 already in Ha), then
// scores = h @ W2 + b2. 1024 blocks x 256 threads; wave = 16 spans.
// Gathers are 16B chunks of 320B rows from H (L2-resident, 10.5MB).
// ---------------------------------------------------------------------------
__global__ __launch_bounds__(256, 4) void k2_span(
    const int* __restrict__ spans, const int* __restrict__ bids,
    const short* __restrict__ H, const short* __restrict__ W2p,
    const float* __restrict__ b2, float* __restrict__ out)
{
  const int tid  = threadIdx.x;
  const int wv   = tid >> 6;
  const int lane = tid & 63;
  const int l15  = lane & 15;
  const int kg   = lane >> 4;
  const int blk  = blockIdx.x;

  // hoist W2 fragments (L1-hot)
  shortx8 wf[5][2];
#pragma unroll
  for (int ks = 0; ks < 5; ++ks)
#pragma unroll
    for (int cb2 = 0; cb2 < 2; ++cb2)
      wf[ks][cb2] = *reinterpret_cast<const shortx8*>(
          W2p + ((ks * 2 + cb2) * 64 + lane) * 8);

  int r  = blk * 64 + wv * 16 + l15;
  int bb = bids[r];
  int rb = bb * TT + spans[2 * r + 0];
  int re = bb * TT + spans[2 * r + 1];
  const short* pa = H + (size_t)rb * 320;         // Ha half (b1 baked in)
  const short* pb = H + (size_t)re * 320 + 160;   // Hb half

  shortx8 af[5];
#pragma unroll
  for (int ks = 0; ks < 5; ++ks) {
    shortx8 ha = *reinterpret_cast<const shortx8*>(pa + ks * 32 + kg * 8);
    shortx8 hb = *reinterpret_cast<const shortx8*>(pb + ks * 32 + kg * 8);
    shortx8 t;
#pragma unroll
    for (int j = 0; j < 8; ++j) {
      float f = bf2f(ha[j]) + bf2f(hb[j]);
      t[j] = f2bf(fmaxf(f, 0.f));
    }
    af[ks] = t;
  }

  f32x4 acc2[2];
  {
    f32x4 z = {0.f, 0.f, 0.f, 0.f};
    acc2[0] = z; acc2[1] = z;
  }
#pragma unroll
  for (int ks = 0; ks < 5; ++ks)
#pragma unroll
    for (int cb2 = 0; cb2 < 2; ++cb2)
      acc2[cb2] = __builtin_amdgcn_mfma_f32_16x16x32_bf16(
          af[ks], wf[ks][cb2], acc2[cb2], 0, 0, 0);

#pragma unroll
  for (int cb2 = 0; cb2 < 2; ++cb2) {
    int col = cb2 * 16 + l15;
    if (col < LL) {
      float bv = b2[col];
#pragma unroll
      for (int i = 0; i < 4; ++i) {
        int row = blk * 64 + wv * 16 + kg * 4 + i;
        out[(size_t)row * LL + col] = acc2[cb2][i] + bv;
      }
    }
  }
}

extern "C" void kernel_launch(void* const* d_in, const int* in_sizes, int n_in,
                              void* d_out, int out_size, void* d_ws, size_t ws_size,
                              hipStream_t stream) {
  const float* xs    = (const float*)d_in[0];
  const int*   spans = (const int*)d_in[1];
  const int*   bids  = (const int*)d_in[2];
  const float* W1    = (const float*)d_in[3];
  const float* b1    = (const float*)d_in[4];
  const float* W2    = (const float*)d_in[5];
  const float* b2    = (const float*)d_in[6];
  float* out = (float*)d_out;

  // ws layout: H [16384][320] bf16 (10,485,760 B) | Bpp (655,360 B) | W2p (10,240 B)
  short* H   = (short*)d_ws;
  short* Bpp = H + 16384 * 320;
  short* W2p = Bpp + 327680;

  prep_w<<<163, 256, 0, stream>>>(W1, W2, Bpp, W2p);
  k1_gemm<<<256, 512, 0, stream>>>(xs, Bpp, b1, H);
  k2_span<<<1024, 256, 0, stream>>>(spans, bids, H, W2p, b2, out);
}

// Round 9
// 135.199 us; speedup vs baseline: 1.5298x; 1.1001x over previous
//
#include <hip/hip_runtime.h>
#include <stdint.h>

#define TT 512
#define DD 1024
#define NN 65536
#define HH 150
#define LL 17

typedef __bf16 bf16_t;
typedef short shortx8 __attribute__((ext_vector_type(8)));
typedef short shortx4 __attribute__((ext_vector_type(4)));
typedef float f32x4 __attribute__((ext_vector_type(4)));

static __device__ __forceinline__ short f2bf(float f) {
  return (short)__builtin_bit_cast(unsigned short, (bf16_t)f);
}
static __device__ __forceinline__ float bf2f(short s) {
  unsigned u = ((unsigned)(unsigned short)s) << 16;
  return __builtin_bit_cast(float, u);
}

// ---------------------------------------------------------------------------
// Prep (UNCHANGED, verified r7): W1 [2048][150] -> Bpp[32 kb][20 cb][64 l][8 j]
//   value = W1[1024*half + kb*32 + (l>>4)*8 + j][hc], cc=cb*16+(l&15),
//   half=cc>=160, hc=cc-160*half, zero if hc>=150.  W2 -> W2p, zero-padded.
// ---------------------------------------------------------------------------
__global__ __launch_bounds__(256) void prep_w(
    const float* __restrict__ W1, const float* __restrict__ W2,
    short* __restrict__ Bpp, short* __restrict__ W2p)
{
  int task = blockIdx.x * 256 + threadIdx.x;
  const int NW1 = 32 * 20 * 64;
  if (task < NW1) {
    int kb  = task / 1280;
    int rem = task - kb * 1280;
    int cb = rem >> 6, l = rem & 63;
    int cc   = cb * 16 + (l & 15);
    int half = (cc >= 160) ? 1 : 0;
    int hc   = cc - 160 * half;
    int krow = half * 1024 + kb * 32 + (l >> 4) * 8;
    shortx8 v;
#pragma unroll
    for (int j = 0; j < 8; ++j) {
      float f = (hc < HH) ? W1[(krow + j) * HH + hc] : 0.f;
      v[j] = f2bf(f);
    }
    *reinterpret_cast<shortx8*>(Bpp + task * 8) = v;
  } else if (task < NW1 + 640) {
    int t2 = task - NW1;
    int kb  = t2 >> 7;
    int rem = t2 & 127;
    int cb = rem >> 6, l = rem & 63;
    int col  = cb * 16 + (l & 15);
    int krow = kb * 32 + (l >> 4) * 8;
    shortx8 v;
#pragma unroll
    for (int j = 0; j < 8; ++j) {
      int r = krow + j;
      float f = (r < HH && col < LL) ? W2[r * LL + col] : 0.f;
      v[j] = f2bf(f);
    }
    *reinterpret_cast<shortx8*>(W2p + t2 * 8) = v;
  }
}

// ---------------------------------------------------------------------------
// K1 v2 (r8 + FIX): H[16384][320] = xs @ [W1a|W1b] (+b1 on Ha).
// 256 blocks x 256 thr (4 waves); block = 64 rows x 320 cols; wave wc =
// 80-col quarter, all 64 rows (rf=4, cbl=5 -> 40 MFMA / 8 ds_read per K64
// chunk = MFMA-bound).
// A: staged ONCE to LDS (reg-stage fp32->bf16, XOR swizzle (row&7)<<4),
//    read by all 4 waves -> xs traffic 64MB exactly once.
// B: fragments read DIRECT global->reg (Bpp L2-resident; per-wave distinct
//    wc quarter), depth-1 chunk prefetch; compiler auto-waitcnts cover reg
//    deps -> only lgkmcnt+barrier per chunk.
// r8 BUG was here: bg offset must be wc*5 *cb-blocks* = wc*5*64 fragments,
// not wc*5 fragments (which lane-shifted waves 1-3 into wrong B data).
// ---------------------------------------------------------------------------
__global__ __launch_bounds__(256, 1) void k1_gemm(
    const float* __restrict__ xs, const short* __restrict__ Bpp,
    const float* __restrict__ b1, short* __restrict__ H)
{
  __shared__ __align__(16) char lds[16384];   // 2 x 8KB A-chunk dbuf

  const int tid  = threadIdx.x;
  const int wc   = tid >> 6;                  // wave = col quarter 0..3
  const int lane = tid & 63;
  const int l15  = lane & 15;
  const int kg   = lane >> 4;
  const int blk  = blockIdx.x;

  // A-stage addressing: thread t covers row t>>2, floats (t&3)*16..+16 of chunk
  const int arow = tid >> 2;
  const int acol = (tid & 3) * 16;
  const float* ag = xs + (size_t)(blk * 64 + arow) * 1024 + acol;
  // LDS write bytes (within 8KB buf): row*128 + (t&3)*32 + {0,16}, swizzled
  const int awb = arow * 128 + (tid & 3) * 32;
  const int aswz_w = (arow & 7) << 4;
  // LDS read base for frags: (rf*16+l15)*128 + s*64 + kg*16, swizzled
  const int arb = l15 * 128 + kg * 16;
  const int aswz_r = (l15 & 7) << 4;

  // FIX (r8 bug): +wc*5 cb-blocks = +wc*5*64 fragments
  const shortx8* bg = reinterpret_cast<const shortx8*>(Bpp) + (size_t)wc * 5 * 64;

  f32x4 acc[4][5];
  {
    f32x4 z = {0.f, 0.f, 0.f, 0.f};
#pragma unroll
    for (int rf = 0; rf < 4; ++rf)
#pragma unroll
      for (int cbl = 0; cbl < 5; ++cbl) acc[rf][cbl] = z;
  }

  f32x4 aregA[4], aregB[4];                   // in-flight fp32 A (16 floats)
  shortx8 bregA[10], bregB[10];               // in-flight B frags (chunk)

#define GLOAD_A(reg, c) do { _Pragma("unroll") \
    for (int i = 0; i < 4; ++i) \
      reg[i] = *reinterpret_cast<const f32x4*>(ag + (c) * 64 + i * 4); \
  } while (0)

#define GLOAD_B(reg, c) do { _Pragma("unroll") \
    for (int s = 0; s < 2; ++s) \
      _Pragma("unroll") \
      for (int cbl = 0; cbl < 5; ++cbl) \
        reg[s * 5 + cbl] = bg[(size_t)((2 * (c) + s) * 20 + cbl) * 64 + lane]; \
  } while (0)

  // cvt 16 fp32 -> 16 bf16, two swizzled b128 stores into buf p
#define WRITE_A(reg, p) do { \
    shortx8 lo_, hi_; \
    _Pragma("unroll") \
    for (int i = 0; i < 8; ++i) { \
      lo_[i] = f2bf(reg[i >> 2][i & 3]); \
      hi_[i] = f2bf(reg[2 + (i >> 2)][i & 3]); \
    } \
    char* b_ = lds + (p) * 8192; \
    *reinterpret_cast<shortx8*>(b_ + ((awb +  0) ^ aswz_w)) = lo_; \
    *reinterpret_cast<shortx8*>(b_ + ((awb + 16) ^ aswz_w)) = hi_; \
  } while (0)

#define COMP(breg, p) do { \
    const char* b_ = lds + (p) * 8192; \
    _Pragma("unroll") \
    for (int s = 0; s < 2; ++s) { \
      shortx8 af_[4]; \
      _Pragma("unroll") \
      for (int rf = 0; rf < 4; ++rf) \
        af_[rf] = *reinterpret_cast<const shortx8*>( \
            b_ + ((arb + rf * 2048 + s * 64) ^ aswz_r)); \
      _Pragma("unroll") \
      for (int rf = 0; rf < 4; ++rf) \
        _Pragma("unroll") \
        for (int cbl = 0; cbl < 5; ++cbl) \
          acc[rf][cbl] = __builtin_amdgcn_mfma_f32_16x16x32_bf16( \
              breg[s * 5 + cbl], af_[rf], acc[rf][cbl], 0, 0, 0); \
    } \
  } while (0)

#define BAR() do { \
    asm volatile("s_waitcnt lgkmcnt(0)" ::: "memory"); \
    __builtin_amdgcn_s_barrier(); \
    __builtin_amdgcn_sched_barrier(0); \
  } while (0)

  // ---- prologue: A(0) -> buf0; B(0), A(1) in flight
  GLOAD_A(aregA, 0);
  WRITE_A(aregA, 0);          // compiler waits the 4 loads before cvt
  GLOAD_B(bregA, 0);
  GLOAD_A(aregB, 1);
  BAR();

  // ---- main loop: 16 chunks of K=64, unrolled x2 for static dbuf indices
#pragma unroll 1
  for (int cp = 0; cp < 8; ++cp) {
    int c0 = 2 * cp;
    // even chunk c0: compute buf0/bregA; stage A(c0+1)->buf1; prefetch B(c0+1), A(c0+2)
    GLOAD_B(bregB, c0 + 1);
    COMP(bregA, 0);
    WRITE_A(aregB, 1);                         // A(c0+1) -> buf1
    if (c0 + 2 < 16) GLOAD_A(aregA, c0 + 2);
    BAR();
    // odd chunk c0+1: compute buf1/bregB; stage A(c0+2)->buf0; prefetch B(c0+2), A(c0+3)
    if (c0 + 2 < 16) GLOAD_B(bregA, c0 + 2);
    COMP(bregB, 1);
    if (c0 + 2 < 16) {
      WRITE_A(aregA, 0);                       // A(c0+2) -> buf0
      if (c0 + 3 < 16) GLOAD_A(aregB, c0 + 3);
      BAR();
    }
  }
#undef GLOAD_A
#undef GLOAD_B
#undef WRITE_A
#undef COMP
#undef BAR

  // ---- epilogue: +b1 (guarded), cvt, store H (verified r7 mapping:
  // row = blk*64 + rf*16 + l15, col = wc*80 + cbl*16 + kg*4 + i)
#pragma unroll
  for (int cbl = 0; cbl < 5; ++cbl) {
    int c0 = wc * 80 + cbl * 16 + kg * 4;
    f32x4 badd;
#pragma unroll
    for (int i = 0; i < 4; ++i)
      badd[i] = (c0 + i < HH) ? b1[c0 + i] : 0.f;
#pragma unroll
    for (int rf = 0; rf < 4; ++rf) {
      f32x4 v = acc[rf][cbl] + badd;
      shortx4 hv;
      hv[0] = f2bf(v[0]); hv[1] = f2bf(v[1]); hv[2] = f2bf(v[2]); hv[3] = f2bf(v[3]);
      int hrow = blk * 64 + rf * 16 + l15;
      *reinterpret_cast<shortx4*>(H + (size_t)hrow * 320 + c0) = hv;
    }
  }
}

// ---------------------------------------------------------------------------
// K2 (UNCHANGED, verified r7): h = relu(Ha[rb] + Hb[re]), scores = h@W2 + b2.
// ---------------------------------------------------------------------------
__global__ __launch_bounds__(256, 4) void k2_span(
    const int* __restrict__ spans, const int* __restrict__ bids,
    const short* __restrict__ H, const short* __restrict__ W2p,
    const float* __restrict__ b2, float* __restrict__ out)
{
  const int tid  = threadIdx.x;
  const int wv   = tid >> 6;
  const int lane = tid & 63;
  const int l15  = lane & 15;
  const int kg   = lane >> 4;
  const int blk  = blockIdx.x;

  shortx8 wf[5][2];
#pragma unroll
  for (int ks = 0; ks < 5; ++ks)
#pragma unroll
    for (int cb2 = 0; cb2 < 2; ++cb2)
      wf[ks][cb2] = *reinterpret_cast<const shortx8*>(
          W2p + ((ks * 2 + cb2) * 64 + lane) * 8);

  int r  = blk * 64 + wv * 16 + l15;
  int bb = bids[r];
  int rb = bb * TT + spans[2 * r + 0];
  int re = bb * TT + spans[2 * r + 1];
  const short* pa = H + (size_t)rb * 320;
  const short* pb = H + (size_t)re * 320 + 160;

  shortx8 af[5];
#pragma unroll
  for (int ks = 0; ks < 5; ++ks) {
    shortx8 ha = *reinterpret_cast<const shortx8*>(pa + ks * 32 + kg * 8);
    shortx8 hb = *reinterpret_cast<const shortx8*>(pb + ks * 32 + kg * 8);
    shortx8 t;
#pragma unroll
    for (int j = 0; j < 8; ++j) {
      float f = bf2f(ha[j]) + bf2f(hb[j]);
      t[j] = f2bf(fmaxf(f, 0.f));
    }
    af[ks] = t;
  }

  f32x4 acc2[2];
  {
    f32x4 z = {0.f, 0.f, 0.f, 0.f};
    acc2[0] = z; acc2[1] = z;
  }
#pragma unroll
  for (int ks = 0; ks < 5; ++ks)
#pragma unroll
    for (int cb2 = 0; cb2 < 2; ++cb2)
      acc2[cb2] = __builtin_amdgcn_mfma_f32_16x16x32_bf16(
          af[ks], wf[ks][cb2], acc2[cb2], 0, 0, 0);

#pragma unroll
  for (int cb2 = 0; cb2 < 2; ++cb2) {
    int col = cb2 * 16 + l15;
    if (col < LL) {
      float bv = b2[col];
#pragma unroll
      for (int i = 0; i < 4; ++i) {
        int row = blk * 64 + wv * 16 + kg * 4 + i;
        out[(size_t)row * LL + col] = acc2[cb2][i] + bv;
      }
    }
  }
}

extern "C" void kernel_launch(void* const* d_in, const int* in_sizes, int n_in,
                              void* d_out, int out_size, void* d_ws, size_t ws_size,
                              hipStream_t stream) {
  const float* xs    = (const float*)d_in[0];
  const int*   spans = (const int*)d_in[1];
  const int*   bids  = (const int*)d_in[2];
  const float* W1    = (const float*)d_in[3];
  const float* b1    = (const float*)d_in[4];
  const float* W2    = (const float*)d_in[5];
  const float* b2    = (const float*)d_in[6];
  float* out = (float*)d_out;

  // ws: H [16384][320] bf16 (10,485,760 B) | Bpp (655,360 B) | W2p (10,240 B)
  short* H   = (short*)d_ws;
  short* Bpp = H + 16384 * 320;
  short* W2p = Bpp + 327680;

  prep_w<<<163, 256, 0, stream>>>(W1, W2, Bpp, W2p);
  k1_gemm<<<256, 256, 0, stream>>>(xs, Bpp, b1, H);
  k2_span<<<1024, 256, 0, stream>>>(spans, bids, H, W2p, b2, out);
}